// Round 2
// baseline (20385.056 us; speedup 1.0000x reference)
//
#include <hip/hip_runtime.h>
#include <cstdint>
#include <cstddef>

// Match XLA elementwise codegen: no implicit mul+add contraction (explicit fmaf
// calls below still emit v_fma, matching XLA's fmuladd usage in fast-tanh).
#pragma clang fp contract(off)

#define DI __device__ __forceinline__

// ---------------- problem sizes ----------------
constexpr int BN = 8192;   // batch
constexpr int TT = 100;    // max_length
constexpr int VV = 100;    // vocab

constexpr size_t HE = (size_t)BN * 256;    // h/c state elems
constexpr size_t GE = (size_t)BN * 1024;   // gate-row elems

// ---------------- workspace layout (floats) ----------------
constexpr size_t OFF_H0    = 0;                       // [2][8192][256] ping-pong
constexpr size_t OFF_H1    = OFF_H0 + 2 * HE;
constexpr size_t OFF_C0    = OFF_H1 + 2 * HE;         // [8192][256]
constexpr size_t OFF_C1    = OFF_C0 + HE;
constexpr size_t OFF_LATH  = OFF_C1 + HE;             // [8192][256]
constexpr size_t OFF_LATC  = OFF_LATH + HE;           // [8192][1024] interleaved gates
constexpr size_t OFF_WTL1  = OFF_LATC + GE;           // [512][1024] (Wih1^T ; Whh1^T) interleaved
constexpr size_t OFF_WTHH0 = OFF_WTL1 + 512 * 1024;   // [256][1024] interleaved
constexpr size_t OFF_WIH0B = OFF_WTHH0 + 256 * 1024;  // [256][1024] interleaved (lat half of W_ih0)
constexpr size_t OFF_WTLP  = OFF_WIH0B + 256 * 1024;  // [512][256]
constexpr size_t OFF_WTOUT = OFF_WTLP + 512 * 256;    // [256][128] zero-padded
constexpr size_t OFF_EMBG  = OFF_WTOUT + 256 * 128;   // [100][1024] interleaved
constexpr size_t OFF_BS0   = OFF_EMBG + 100 * 1024;   // [1024] b_ih0+b_hh0 interleaved
constexpr size_t OFF_B1S   = OFF_BS0 + 1024;          // [1024] b_ih1+b_hh1 interleaved
constexpr size_t OFF_KEYS  = OFF_B1S + 1024;          // 100 x uint2 step keys (256 floats reserved)
constexpr size_t OFF_TOK   = OFF_KEYS + 256;          // [8192] int32 tokens

// ---------------- JAX threefry2x32 (partitionable semantics) ----------------
DI uint32_t rotl32(uint32_t x, int r) { return (x << r) | (x >> (32 - r)); }

DI void tf2x32(uint32_t k0, uint32_t k1, uint32_t x0, uint32_t x1,
               uint32_t& o0, uint32_t& o1) {
  uint32_t ks2 = 0x1BD11BDAu ^ k0 ^ k1;
  x0 += k0; x1 += k1;
#define TFR(R) { x0 += x1; x1 = rotl32(x1, R); x1 ^= x0; }
  TFR(13) TFR(15) TFR(26) TFR(6)
  x0 += k1; x1 += ks2 + 1u;
  TFR(17) TFR(29) TFR(16) TFR(24)
  x0 += ks2; x1 += k0 + 2u;
  TFR(13) TFR(15) TFR(26) TFR(6)
  x0 += k0; x1 += k1 + 3u;
  TFR(17) TFR(29) TFR(16) TFR(24)
  x0 += k1; x1 += ks2 + 4u;
  TFR(13) TFR(15) TFR(26) TFR(6)
  x0 += ks2; x1 += k0 + 5u;
#undef TFR
  o0 = x0; o1 = x1;
}

// gumbel noise exactly as jax.random.gumbel (partitionable random_bits: o0^o1)
DI float gumbelv(uint2 key, uint32_t idx) {
  uint32_t o0, o1;
  tf2x32(key.x, key.y, 0u, idx, o0, o1);
  uint32_t bits = o0 ^ o1;
  float u0 = __uint_as_float((bits >> 9) | 0x3f800000u) - 1.0f;
  const float tiny = 1.1754943508222875e-38f;
  float u = fmaxf(tiny, u0 + tiny);   // (1-tiny) rounds to 1.0f, so scale is +tiny
  return -logf(-logf(u));
}

// XLA EmitFastTanh (f32): |x|<4e-4 -> x ; clamp +-9 ; rational p/q with fma
DI float xtanh(float x) {
  float ax = fabsf(x);
  float xc = fminf(fmaxf(x, -9.0f), 9.0f);
  float x2 = xc * xc;
  float num = -2.76076847742355e-16f;
  num = fmaf(num, x2, 2.00018790482477e-13f);
  num = fmaf(num, x2, -8.60467152213735e-11f);
  num = fmaf(num, x2, 5.12229709037114e-08f);
  num = fmaf(num, x2, 1.48572235717979e-05f);
  num = fmaf(num, x2, 6.37261928875436e-04f);
  num = fmaf(num, x2, 4.89352455891786e-03f);
  num = xc * num;
  float den = 1.19825839466702e-06f;
  den = fmaf(den, x2, 1.18534705686654e-04f);
  den = fmaf(den, x2, 2.26843463243900e-03f);
  den = fmaf(den, x2, 4.89352518554385e-03f);
  return (ax < 0.0004f) ? x : (num / den);
}

// XLA logistic_expander: 1 / (1 + exp(-x))
DI float xsig(float x) { return 1.0f / (1.0f + expf(-x)); }

// ---------------- init / transpose kernels ----------------

// dst[k*1024 + j*4+g] = src[(g*256+j)*srcld + koff + k]   (gate-interleaved B^T)
__global__ void k_tr_gates(const float* __restrict__ src, float* __restrict__ dst,
                           int srcld, int koff) {
  int id = blockIdx.x * 256 + threadIdx.x;        // 256*1024 total
  int k = id >> 10, n = id & 1023, j = n >> 2, g = n & 3;
  dst[id] = src[(size_t)(g * 256 + j) * srcld + koff + k];
}

// dst[k*dstld + n] = (n < rows) ? src[n*cols + k] : 0
__global__ void k_tr_plain(const float* __restrict__ src, float* __restrict__ dst,
                           int rows, int cols, int dstld) {
  int id = blockIdx.x * 256 + threadIdx.x;
  int k = id / dstld, n = id % dstld;
  dst[id] = (n < rows) ? src[(size_t)n * cols + k] : 0.0f;
}

__global__ void k_init_misc(const float* __restrict__ b_ih0, const float* __restrict__ b_hh0,
                            const float* __restrict__ b_ih1, const float* __restrict__ b_hh1,
                            float* __restrict__ bs0, float* __restrict__ b1s,
                            uint2* __restrict__ keys, int* __restrict__ tok) {
  int id = blockIdx.x * 256 + threadIdx.x;
  if (id < 1024) {
    int j = id >> 2, g = id & 3;
    bs0[id] = b_ih0[g * 256 + j] + b_hh0[g * 256 + j];
  } else if (id < 2048) {
    int n = id - 1024, j = n >> 2, g = n & 3;
    b1s[n] = b_ih1[g * 256 + j] + b_hh1[g * 256 + j];
  } else if (id >= 2048 && id < 2048 + TT) {
    // step keys: jax.random.split(key(42), T) partitionable: threefry((0,42),(0,t))
    uint32_t o0, o1;
    tf2x32(0u, 42u, 0u, (uint32_t)(id - 2048), o0, o1);
    keys[id - 2048] = make_uint2(o0, o1);
  }
  if (id >= 4096 && id < 4096 + BN) tok[id - 4096] = 1;  // START_TOKEN
}

// emb_gate[v][j*4+g] = sum_k embedding[v][k] * W_ih0[(g*256+j)][k]
__global__ void k_embgate(const float* __restrict__ emb, const float* __restrict__ W_ih0,
                          float* __restrict__ out) {
  int v = blockIdx.x;
  int n = blockIdx.y * 256 + threadIdx.x;
  int j = n >> 2, g = n & 3;
  const float* wr = &W_ih0[(size_t)(g * 256 + j) * 512];
  const float* er = &emb[(size_t)v * 256];
  float s = 0.0f;
  for (int k = 0; k < 256; ++k) s = fmaf(er[k], wr[k], s);
  out[(size_t)v * 1024 + n] = s;
}

// ---------------- fused GEMM (+ optional LSTM cell epilogue) ----------------
// C[M][N] tile 64x128, block 256 threads (tn=tid&31 -> 4 cols, tm=tid>>5 -> 8 rows), KC=32.
// MODE 0: C = A@B + bias[N]
// MODE 1: layer-0 cell: gates = A@B + lat_c[r] + emb_gate[tok[r]]; h/c update
// MODE 2: layer-1 cell: gates = [A0|A1]@B + bias[N]; h/c update
template <int MODE>
__global__ __launch_bounds__(256)
void k_gemm(const float* __restrict__ A0, const float* __restrict__ A1,
            int lda, int Ksplit, int K,
            const float* __restrict__ Bw, int N,
            const float* __restrict__ ext, const float* __restrict__ embg,
            const int* __restrict__ tokin,
            float* __restrict__ Cout, float* __restrict__ cstate) {
  __shared__ float As[32][68];    // [k][row], padded: 68*4B stride keeps 16B align
  __shared__ float Bs[32][128];
  const int tid = threadIdx.x;
  const int tn = tid & 31, tm = tid >> 5;
  const int row0 = blockIdx.x * 64;
  const int col0 = blockIdx.y * 128;
  const int lrow = tid >> 3, lk4 = (tid & 7) << 2;
  float acc[8][4] = {};

  for (int k0 = 0; k0 < K; k0 += 32) {
    const float* Ap; int kb;
    if (k0 < Ksplit) { Ap = A0; kb = k0; } else { Ap = A1; kb = k0 - Ksplit; }
    __syncthreads();
#pragma unroll
    for (int rr = 0; rr < 2; ++rr) {
      int r = lrow + rr * 32;
      const float4 v = *(const float4*)&Ap[(size_t)(row0 + r) * lda + kb + lk4];
      As[lk4 + 0][r] = v.x; As[lk4 + 1][r] = v.y;
      As[lk4 + 2][r] = v.z; As[lk4 + 3][r] = v.w;
    }
#pragma unroll
    for (int it = 0; it < 4; ++it) {
      int k = tm + it * 8;
      *(float4*)&Bs[k][tn << 2] = *(const float4*)&Bw[(size_t)(k0 + k) * N + col0 + (tn << 2)];
    }
    __syncthreads();
#pragma unroll
    for (int kk = 0; kk < 32; ++kk) {
      float a[8];
      {
        float4 t0 = *(const float4*)&As[kk][tm * 8];
        float4 t1 = *(const float4*)&As[kk][tm * 8 + 4];
        a[0] = t0.x; a[1] = t0.y; a[2] = t0.z; a[3] = t0.w;
        a[4] = t1.x; a[5] = t1.y; a[6] = t1.z; a[7] = t1.w;
      }
      float4 b4 = *(const float4*)&Bs[kk][tn << 2];
#pragma unroll
      for (int i = 0; i < 8; ++i) {
        acc[i][0] = fmaf(a[i], b4.x, acc[i][0]);
        acc[i][1] = fmaf(a[i], b4.y, acc[i][1]);
        acc[i][2] = fmaf(a[i], b4.z, acc[i][2]);
        acc[i][3] = fmaf(a[i], b4.w, acc[i][3]);
      }
    }
  }

  const int col = col0 + (tn << 2);
  if (MODE == 0) {
    float4 bv = *(const float4*)&ext[col];
#pragma unroll
    for (int i = 0; i < 8; ++i) {
      int r = row0 + tm * 8 + i;
      float4 o;
      o.x = acc[i][0] + bv.x; o.y = acc[i][1] + bv.y;
      o.z = acc[i][2] + bv.z; o.w = acc[i][3] + bv.w;
      *(float4*)&Cout[(size_t)r * N + col] = o;
    }
  } else {
    const int j = col >> 2;   // h index
#pragma unroll
    for (int i = 0; i < 8; ++i) {
      int r = row0 + tm * 8 + i;
      float gi, gf, gg, go;
      if (MODE == 1) {
        float4 lc = *(const float4*)&ext[(size_t)r * 1024 + col];
        float4 e  = *(const float4*)&embg[(size_t)tokin[r] * 1024 + col];
        gi = acc[i][0] + lc.x + e.x; gf = acc[i][1] + lc.y + e.y;
        gg = acc[i][2] + lc.z + e.z; go = acc[i][3] + lc.w + e.w;
      } else {
        float4 bv = *(const float4*)&ext[col];
        gi = acc[i][0] + bv.x; gf = acc[i][1] + bv.y;
        gg = acc[i][2] + bv.z; go = acc[i][3] + bv.w;
      }
      float cold = cstate[(size_t)r * 256 + j];
      float t1 = xsig(gf) * cold;
      float t2 = xsig(gi) * xtanh(gg);
      float cn = t1 + t2;
      float hn = xsig(go) * xtanh(cn);
      cstate[(size_t)r * 256 + j] = cn;
      Cout[(size_t)r * 256 + j] = hn;
    }
  }
}

// ---------------- logits + categorical sampling ----------------
// tile 32 rows x 128 cols (V padded to 128); tn=tid&31 -> 4 cols, tm=tid>>5 -> 4 rows
__global__ __launch_bounds__(256)
void k_logits(const float* __restrict__ h1, const float* __restrict__ Bw /*[256][128]*/,
              const float* __restrict__ bout, float* __restrict__ out,
              int* __restrict__ tok, const uint2* __restrict__ keys, int t) {
  __shared__ float As[32][36];
  __shared__ float Bs[32][128];
  const int tid = threadIdx.x;
  const int tn = tid & 31, tm = tid >> 5;
  const int row0 = blockIdx.x * 32;
  const int lrow = tid >> 3, lk4 = (tid & 7) << 2;
  float acc[4][4] = {};

  for (int k0 = 0; k0 < 256; k0 += 32) {
    __syncthreads();
    {
      const float4 v = *(const float4*)&h1[(size_t)(row0 + lrow) * 256 + k0 + lk4];
      As[lk4 + 0][lrow] = v.x; As[lk4 + 1][lrow] = v.y;
      As[lk4 + 2][lrow] = v.z; As[lk4 + 3][lrow] = v.w;
    }
#pragma unroll
    for (int it = 0; it < 4; ++it) {
      int k = tm + it * 8;
      *(float4*)&Bs[k][tn << 2] = *(const float4*)&Bw[(size_t)(k0 + k) * 128 + (tn << 2)];
    }
    __syncthreads();
#pragma unroll
    for (int kk = 0; kk < 32; ++kk) {
      float4 a4 = *(const float4*)&As[kk][tm << 2];
      float4 b4 = *(const float4*)&Bs[kk][tn << 2];
      float a[4] = {a4.x, a4.y, a4.z, a4.w};
#pragma unroll
      for (int i = 0; i < 4; ++i) {
        acc[i][0] = fmaf(a[i], b4.x, acc[i][0]);
        acc[i][1] = fmaf(a[i], b4.y, acc[i][1]);
        acc[i][2] = fmaf(a[i], b4.z, acc[i][2]);
        acc[i][3] = fmaf(a[i], b4.w, acc[i][3]);
      }
    }
  }

  const uint2 kt = keys[t];
  const int vb = tn << 2;
#pragma unroll
  for (int i = 0; i < 4; ++i) {
    int r = row0 + (tm << 2) + i;
    float lg[4];
#pragma unroll
    for (int q = 0; q < 4; ++q)
      lg[q] = acc[i][q] + ((vb + q < VV) ? bout[vb + q] : 0.0f);
    if (vb < VV) {  // vb multiple of 4, VV=100 -> exact float4 coverage
      *(float4*)&out[(size_t)r * (TT * VV) + (size_t)t * VV + vb] =
          make_float4(lg[0], lg[1], lg[2], lg[3]);
    }
    // gumbel-max sampling (first-max tie-break like jnp.argmax)
    float bv = -3.4e38f; int bi = 0x7fffffff;
#pragma unroll
    for (int q = 0; q < 4; ++q) {
      int v = vb + q;
      if (v < VV) {
        float g = gumbelv(kt, (uint32_t)(r * VV + v));
        float val = lg[q] + g;
        if (val > bv) { bv = val; bi = v; }
      }
    }
    for (int off = 16; off > 0; off >>= 1) {
      float ov = __shfl_xor(bv, off, 32);
      int   oi = __shfl_xor(bi, off, 32);
      if (ov > bv || (ov == bv && oi < bi)) { bv = ov; bi = oi; }
    }
    if (tn == 0) tok[r] = bi;
  }
}

// ---------------- launch ----------------
extern "C" void kernel_launch(void* const* d_in, const int* in_sizes, int n_in,
                              void* d_out, int out_size, void* d_ws, size_t ws_size,
                              hipStream_t stream) {
  const float* latent    = (const float*)d_in[0];
  const float* embedding = (const float*)d_in[1];
  const float* W_lp  = (const float*)d_in[2];
  const float* b_lp  = (const float*)d_in[3];
  const float* W_ih0 = (const float*)d_in[4];
  const float* W_hh0 = (const float*)d_in[5];
  const float* b_ih0 = (const float*)d_in[6];
  const float* b_hh0 = (const float*)d_in[7];
  const float* W_ih1 = (const float*)d_in[8];
  const float* W_hh1 = (const float*)d_in[9];
  const float* b_ih1 = (const float*)d_in[10];
  const float* b_hh1 = (const float*)d_in[11];
  const float* W_out = (const float*)d_in[12];
  const float* b_out = (const float*)d_in[13];
  float* out = (float*)d_out;
  float* ws  = (float*)d_ws;

  float* h0     = ws + OFF_H0;
  float* h1     = ws + OFF_H1;
  float* c0     = ws + OFF_C0;
  float* c1     = ws + OFF_C1;
  float* lat_h  = ws + OFF_LATH;
  float* lat_c  = ws + OFF_LATC;
  float* WtL1   = ws + OFF_WTL1;
  float* WtHH0  = ws + OFF_WTHH0;
  float* WiH0b  = ws + OFF_WIH0B;
  float* WtLP   = ws + OFF_WTLP;
  float* WtOUT  = ws + OFF_WTOUT;
  float* embg   = ws + OFF_EMBG;
  float* bs0    = ws + OFF_BS0;
  float* b1s    = ws + OFF_B1S;
  uint2* keys   = (uint2*)(ws + OFF_KEYS);
  int*   tok    = (int*)(ws + OFF_TOK);

  // zero initial states (ws is poisoned 0xAA before every timed launch)
  hipMemsetAsync(h0, 0, HE * sizeof(float), stream);
  hipMemsetAsync(h1, 0, HE * sizeof(float), stream);
  hipMemsetAsync(c0, 0, HE * sizeof(float), stream);
  hipMemsetAsync(c1, 0, HE * sizeof(float), stream);

  // weight repacks (gate-interleaved B^T layouts)
  k_tr_gates<<<1024, 256, 0, stream>>>(W_hh0, WtHH0, 256, 0);
  k_tr_gates<<<1024, 256, 0, stream>>>(W_ih1, WtL1, 256, 0);
  k_tr_gates<<<1024, 256, 0, stream>>>(W_hh1, WtL1 + 256 * 1024, 256, 0);
  k_tr_gates<<<1024, 256, 0, stream>>>(W_ih0, WiH0b, 512, 256);
  k_tr_plain<<<512, 256, 0, stream>>>(W_lp, WtLP, 256, 512, 256);
  k_tr_plain<<<128, 256, 0, stream>>>(W_out, WtOUT, VV, 256, 128);
  k_init_misc<<<48, 256, 0, stream>>>(b_ih0, b_hh0, b_ih1, b_hh1, bs0, b1s, keys, tok);

  // lat_h = latent @ W_lp^T + b_lp          [8192,512]x[512,256]
  k_gemm<0><<<dim3(128, 2), 256, 0, stream>>>(latent, latent, 512, 512, 512,
                                              WtLP, 256, b_lp, nullptr, nullptr,
                                              lat_h, nullptr);
  // lat_c = lat_h @ W_ih0[:,256:]^T + b_ih0 + b_hh0   (interleaved) [8192,1024]
  k_gemm<0><<<dim3(128, 8), 256, 0, stream>>>(lat_h, lat_h, 256, 256, 256,
                                              WiH0b, 1024, bs0, nullptr, nullptr,
                                              lat_c, nullptr);
  // emb_gate[v] = embedding[v] @ W_ih0[:,:256]^T      (interleaved) [100,1024]
  k_embgate<<<dim3(100, 4), 256, 0, stream>>>(embedding, W_ih0, embg);

  for (int t = 0; t < TT; ++t) {
    float* h0r = h0 + (size_t)(t & 1) * HE;
    float* h0w = h0 + (size_t)((t + 1) & 1) * HE;
    float* h1r = h1 + (size_t)(t & 1) * HE;
    float* h1w = h1 + (size_t)((t + 1) & 1) * HE;
    // layer 0: gates = h0@W_hh0^T + lat_c + emb_gate[tok]; cell update
    k_gemm<1><<<dim3(128, 8), 256, 0, stream>>>(h0r, h0r, 256, 256, 256,
                                                WtHH0, 1024, lat_c, embg, tok,
                                                h0w, c0);
    // layer 1: gates = h0'@W_ih1^T + h1@W_hh1^T + b1s; cell update
    k_gemm<2><<<dim3(128, 8), 256, 0, stream>>>(h0w, h1r, 256, 256, 512,
                                                WtL1, 1024, b1s, nullptr, nullptr,
                                                h1w, c1);
    // logits + write output + categorical sample
    k_logits<<<256, 256, 0, stream>>>(h1w, WtOUT, b_out, out, tok, keys, t);
  }
}